// Round 6
// baseline (286.870 us; speedup 1.0000x reference)
//
#include <hip/hip_runtime.h>
#include <math.h>

#define DD 512
#define HG 64
#define M_ROWS 32768                    // 8*64*64
#define ELEMS ((size_t)M_ROWS * DD)
#define LOG2E 1.44269504088896340736f

typedef __attribute__((ext_vector_type(8))) _Float16 f16x8;
typedef __attribute__((ext_vector_type(2))) _Float16 f16x2;
typedef __attribute__((ext_vector_type(4))) float f32x4;

__device__ __forceinline__ float fexp2_(float x) { return __builtin_amdgcn_exp2f(x); }
__device__ __forceinline__ float frcp_(float x)  { return __builtin_amdgcn_rcpf(x); }
// sigmoid(v) = 1/(1+exp2(-v*log2e)); inf-safe: exp2->inf => rcp->0
__device__ __forceinline__ float fsig_(float v)  { return frcp_(1.0f + fexp2_(-v * LOG2E)); }

// Fused prep: blocks [0,8192) convert x fp32->fp16; blocks [8192,8448)
// transpose+convert the four 512x512 weights into WT (fp16, N-major).
__global__ __launch_bounds__(256) void prep(
    const float* __restrict__ x, _Float16* __restrict__ x16,
    const float* __restrict__ W0, const float* __restrict__ W1,
    const float* __restrict__ W2, const float* __restrict__ W3,
    _Float16* __restrict__ WT)
{
    __shared__ float tile[64][65];
    if (blockIdx.x < 8192) {
        const size_t i = ((size_t)blockIdx.x * 256 + threadIdx.x) * 8;
        const float4 a = *(const float4*)&x[i];
        const float4 b = *(const float4*)&x[i + 4];
        f16x8 h;
        h[0] = (_Float16)a.x; h[1] = (_Float16)a.y;
        h[2] = (_Float16)a.z; h[3] = (_Float16)a.w;
        h[4] = (_Float16)b.x; h[5] = (_Float16)b.y;
        h[6] = (_Float16)b.z; h[7] = (_Float16)b.w;
        *(f16x8*)&x16[i] = h;
        return;
    }
    const int wb = blockIdx.x - 8192;       // 0..255
    const int z = wb >> 6;
    const int rem = wb & 63;
    const int n0 = (rem & 7) * 64, k0 = (rem >> 3) * 64;
    const float* W = (z == 0) ? W0 : (z == 1) ? W1 : (z == 2) ? W2 : W3;
    _Float16* dst = WT + (size_t)z * DD * DD;
    const int t = threadIdx.x;
    const int tr = t >> 6, tc = t & 63;
#pragma unroll
    for (int p = 0; p < 16; ++p)
        tile[p * 4 + tr][tc] = W[(size_t)(k0 + p * 4 + tr) * DD + n0 + tc];
    __syncthreads();
#pragma unroll
    for (int p = 0; p < 16; ++p) {
        const int nn = p * 4 + tr;
        dst[(size_t)(n0 + nn) * DD + k0 + tc] = (_Float16)tile[tc][nn];
    }
}

// ---------------------------------------------------------------------------
// 256x256 fp16 GEMM — faithful m201-style phase machine.
// K=512 = 8 K64-tiles x 4 phases.  Per phase:
//   {4-8 ds_read_b128 || 2 global_load_lds} -> s_barrier
//   -> lgkmcnt(0)+sched_barrier(0) -> setprio(1) 16xMFMA setprio(0)
//   -> [VM only at phases 2,4] -> s_barrier
// LDS: 4 x BK=32 sub-tile buffers (2 K64-tiles deep), XOR-chunk swizzle
// (proven 0-conflict r5), staged via linear-dest global_load_lds with
// pre-swizzled source.  vmcnt ledger: prologue VM(8); T0ph2 VM(8);
// steady VM(4)@ph2,ph4; T7ph2 VM(0).  Frags: fa[4] reloaded per phase,
// fb[2][4] per k-sub; all indices compile-time (rule #20).
// MODE 0: A=x16, WT=[W_f|W_in|W_g]^T (N=1536), epilogues dm/u/g (fp16).
// MODE 1: A=v, WT=W_out^T (N=512), out f32 + bias.
// ---------------------------------------------------------------------------
template <int MODE>
__global__ __launch_bounds__(512, 2) void gemm8p(
    const _Float16* __restrict__ A, const _Float16* __restrict__ WT,
    const float* __restrict__ b0, const float* __restrict__ b1,
    const float* __restrict__ b2, const float* __restrict__ lb_ptr,
    void* __restrict__ o0, void* __restrict__ o1, void* __restrict__ o2)
{
    __shared__ __align__(16) _Float16 As[4][256][32];
    __shared__ __align__(16) _Float16 Bs[4][256][32];

    const int NB = (MODE == 0) ? 6 : 2;
    const int lin = blockIdx.x;
    const int xcd = lin & 7;
    const int qq  = lin >> 3;
    const int n_idx = qq % NB;
    const int mq  = qq / NB;
    const int m0 = (xcd + 8 * mq) * 256;      // same XCD -> same A strip
    const int n0 = n_idx * 256;

    const int tid  = threadIdx.x;
    const int wv   = tid >> 6;                // 0..7
    const int lane = tid & 63;
    const int wm = wv >> 2, wn = wv & 3;      // 2 x 4 wave grid
    const int lrow = lane & 15;
    const int lk   = lane >> 4;               // k-chunk 0..3 (8 f16 each)

    // staging: wave wv owns rows wv*32..wv*32+31; lane l -> row +=(l>>2),
    // LDS chunk (l&3).  Source chunk pre-swizzled: (l&3) ^ ((l>>3)&3).
    const int srow = wv * 32 + (lane >> 2);
    const int schk = ((lane & 3) ^ ((lane >> 3) & 3)) * 8;
    const _Float16* Ag = A  + (size_t)(m0 + srow) * DD + schk;
    const _Float16* Bg = WT + (size_t)(n0 + srow) * DD + schk;

    // fragment read chunk: lk ^ ((lrow>>1)&3)
    const int ksw = (lk ^ ((lrow >> 1) & 3)) * 8;

    f32x4 acc[8][4];
#pragma unroll
    for (int i = 0; i < 8; ++i)
#pragma unroll
        for (int j = 0; j < 4; ++j) acc[i][j] = (f32x4)(0.f);

    f16x8 fa[4], fb[2][4];

#define STGA(J_) do {                                                          \
    _Pragma("unroll")                                                          \
    for (int j_ = 0; j_ < 2; ++j_)                                             \
        __builtin_amdgcn_global_load_lds(                                      \
            (const __attribute__((address_space(1))) void*)                    \
              (Ag + (size_t)(j_ * 16) * DD + (J_) * 32),                       \
            (__attribute__((address_space(3))) void*)                          \
              &As[(J_) & 3][wv * 32 + j_ * 16][0], 16, 0, 0);                  \
    } while (0)

#define STGB(J_) do {                                                          \
    _Pragma("unroll")                                                          \
    for (int j_ = 0; j_ < 2; ++j_)                                             \
        __builtin_amdgcn_global_load_lds(                                      \
            (const __attribute__((address_space(1))) void*)                    \
              (Bg + (size_t)(j_ * 16) * DD + (J_) * 32),                       \
            (__attribute__((address_space(3))) void*)                          \
              &Bs[(J_) & 3][wv * 32 + j_ * 16][0], 16, 0, 0);                  \
    } while (0)

#define LDFA(H_, BUF_) do {                                                    \
    _Pragma("unroll")                                                          \
    for (int q_ = 0; q_ < 4; ++q_)                                             \
        fa[q_] = *(const f16x8*)                                               \
            &As[BUF_][wm * 128 + (H_) * 64 + q_ * 16 + lrow][ksw];             \
    } while (0)

#define LDFB(KS_, BUF_) do {                                                   \
    _Pragma("unroll")                                                          \
    for (int n_ = 0; n_ < 4; ++n_)                                             \
        fb[KS_][n_] = *(const f16x8*)                                          \
            &Bs[BUF_][wn * 64 + n_ * 16 + lrow][ksw];                          \
    } while (0)

#define MM16(H_, KS_) do {                                                     \
    __builtin_amdgcn_s_setprio(1);                                             \
    _Pragma("unroll")                                                          \
    for (int q_ = 0; q_ < 4; ++q_)                                             \
    _Pragma("unroll")                                                          \
    for (int n_ = 0; n_ < 4; ++n_)                                             \
        acc[(H_) * 4 + q_][n_] = __builtin_amdgcn_mfma_f32_16x16x32_f16(       \
            fa[q_], fb[KS_][n_], acc[(H_) * 4 + q_][n_], 0, 0, 0);             \
    __builtin_amdgcn_s_setprio(0);                                             \
    } while (0)

#define BAR   __builtin_amdgcn_s_barrier()
#define LGKM0 do { asm volatile("s_waitcnt lgkmcnt(0)" ::: "memory");          \
                   __builtin_amdgcn_sched_barrier(0); } while (0)
#define VM(N_) asm volatile("s_waitcnt vmcnt(" #N_ ")" ::: "memory")
#define NOSYNC ((void)0)

#define PHASE(LDS_, STG_, H_, KS_, TAIL_) do {                                 \
    LDS_; STG_;                                                                \
    BAR;                                                                       \
    LGKM0;                                                                     \
    MM16(H_, KS_);                                                             \
    TAIL_;                                                                     \
    BAR;                                                                       \
    } while (0)

    // prologue: sub-tiles j=0,1,2 (12 loads/wave); retire j0 -> VM(8).
    STGA(0); STGB(0); STGA(1); STGB(1); STGA(2); STGB(2);
    VM(8); BAR;

    // T=0: reads j0 (buf0), j1 (buf1); stages j3 (buf3).
    PHASE({ LDFA(0, 0); LDFB(0, 0); }, STGA(3), 0, 0, NOSYNC);
    PHASE(  LDFA(1, 0),               STGB(3), 1, 0, VM(8));
    PHASE({ LDFA(0, 1); LDFB(1, 1); }, NOSYNC,  0, 1, NOSYNC);
    PHASE(  LDFA(1, 1),               NOSYNC,  1, 1, VM(4));

    // T=1..6: reads j=2T (bufA), 2T+1 (bufB); stages j=2T+2, 2T+3.
#pragma unroll
    for (int T = 1; T < 7; ++T) {
        const int bA = (2 * T) & 3, bB = (2 * T + 1) & 3;
        const int jA = 2 * T + 2,   jB = 2 * T + 3;
        PHASE({ LDFA(0, bA); LDFB(0, bA); }, STGA(jA), 0, 0, NOSYNC);
        PHASE(  LDFA(1, bA),                STGB(jA), 1, 0, VM(4));
        PHASE({ LDFA(0, bB); LDFB(1, bB); }, STGA(jB), 0, 1, NOSYNC);
        PHASE(  LDFA(1, bB),                STGB(jB), 1, 1, VM(4));
    }

    // T=7: reads j14 (buf2), j15 (buf3); no stages; drain at ph2.
    PHASE({ LDFA(0, 2); LDFB(0, 2); }, NOSYNC, 0, 0, NOSYNC);
    PHASE(  LDFA(1, 2),               NOSYNC, 1, 0, VM(0));
    PHASE({ LDFA(0, 3); LDFB(1, 3); }, NOSYNC, 0, 1, NOSYNC);
    // final cluster: no trailing sync needed before epilogue (acc is per-thread)
    LDFA(1, 3);
    LGKM0;
    MM16(1, 1);

#undef STGA
#undef STGB
#undef LDFA
#undef LDFB
#undef MM16
#undef BAR
#undef LGKM0
#undef VM
#undef NOSYNC
#undef PHASE

    // epilogue: row = m0 + wm*128 + q*16 + lk*4 + r;  col = wn*64 + n*16 + lrow
    if (MODE == 0) {
        const int seg = n_idx >> 1;
        const float lbv = lb_ptr[0];
        const float* bias = (seg == 0) ? b0 : (seg == 1) ? b1 : b2;
        _Float16* outp = (seg == 0) ? (_Float16*)o0
                       : (seg == 1) ? (_Float16*)o1 : (_Float16*)o2;
        const int cbase = (n_idx & 1) * 256 + wn * 64;
#pragma unroll
        for (int q = 0; q < 8; ++q) {
            const int row = m0 + wm * 128 + q * 16 + lk * 4;
#pragma unroll
            for (int n = 0; n < 4; ++n) {
                const int col = cbase + n * 16 + lrow;
                const float bcol = bias[col];
#pragma unroll
                for (int r = 0; r < 4; ++r) {
                    const float v = acc[q][n][r] + bcol;
                    float res;
                    if (seg == 0)      res = (1.0f - lbv) * frcp_(1.0f + fexp2_(v * LOG2E));
                    else if (seg == 1) res = v * fsig_(v);
                    else               res = fsig_(v);
                    outp[(size_t)(row + r) * DD + col] = (_Float16)res;
                }
            }
        }
    } else {
        float* outp = (float*)o0;
#pragma unroll
        for (int q = 0; q < 8; ++q) {
            const int row = m0 + wm * 128 + q * 16 + lk * 4;
#pragma unroll
            for (int n = 0; n < 4; ++n) {
                const int col = n0 + wn * 64 + n * 16 + lrow;
                const float bcol = b0[col];
#pragma unroll
                for (int r = 0; r < 4; ++r)
                    outp[(size_t)(row + r) * DD + col] = acc[q][n][r] + bcol;
            }
        }
    }
}

// Chunk-parallel bidirectional scan. 64-step line split into CH=4 chunks of
// CL=16; linear recurrence => exact carry fix-up via LDS exchange.
// Blocks [0,2048): axis-1 (j) -> ha.  [2048,4096): axis-0 (i) -> hb.
// Each block: one line x 64 d-pairs x 4 chunks (tid = chunk*64 + dpl).
// lam = 1-dm, inp = dm*u; y <- lam*(rot y) + inp; out = fwd + bwd.
#define CH 4
#define CL 16

#define STEP(K, YR0, YI0, YR1, YI1) {                                      \
    const float dm0_ = (float)dmr[K][0], dm1_ = (float)dmr[K][1];          \
    const float lm0_ = 1.0f - dm0_, lm1_ = 1.0f - dm1_;                    \
    float nr_ = fmaf(lm0_, c0 * (YR0) - s0 * (YI0), dm0_ * (float)ur[K][0]); \
    YI0 = lm0_ * (c0 * (YI0) + s0 * (YR0)); YR0 = nr_;                     \
    nr_ = fmaf(lm1_, c1 * (YR1) - s1 * (YI1), dm1_ * (float)ur[K][1]);     \
    YI1 = lm1_ * (c1 * (YI1) + s1 * (YR1)); YR1 = nr_; }

__global__ __launch_bounds__(256, 4) void scan2(
    const _Float16* __restrict__ dm, const _Float16* __restrict__ u,
    const float* __restrict__ theta,
    _Float16* __restrict__ ha, _Float16* __restrict__ hb)
{
    __shared__ float ex[CH][64][13];   // pad 12->13: stride coprime w/ 32 banks

    const int blk  = blockIdx.x & 2047;
    const bool is_i = blockIdx.x >= 2048;
    const int tid   = threadIdx.x;
    const int chunk = tid >> 6;        // 0..3 (wave-uniform)
    const int dpl   = tid & 63;
    const int dpg   = blk & 3;         // 4 groups of 64 d-pairs
    const int line  = blk >> 2;        // 0..511
    const int d0    = (dpg * 64 + dpl) * 2;

    size_t base, stride;
    _Float16* hout;
    if (!is_i) {
        base = (size_t)line * (HG * DD) + d0; stride = DD; hout = ha;
    } else {
        const int bb = line >> 6, j = line & 63;
        base = (size_t)bb * (HG * HG * DD) + (size_t)j * DD + d0;
        stride = (size_t)HG * DD; hout = hb;
    }
    const size_t cbase = base + (size_t)(chunk * CL) * stride;

    float s0, c0, s1, c1;
    sincosf(theta[d0], &s0, &c0);
    sincosf(theta[d0 + 1], &s1, &c1);

    // stage the chunk's dm/u into registers (single global read per element)
    f16x2 dmr[CL], ur[CL];
#pragma unroll
    for (int k = 0; k < CL; ++k) {
        dmr[k] = *(const f16x2*)&dm[cbase + (size_t)k * stride];
        ur[k]  = *(const f16x2*)&u [cbase + (size_t)k * stride];
    }

    // Pass A: zero-init local fwd & bwd scans + decay magnitude product
    float fr0 = 0.f, fi0 = 0.f, fr1 = 0.f, fi1 = 0.f;
    float P0 = 1.f, P1 = 1.f;
#pragma unroll
    for (int k = 0; k < CL; ++k) {
        const float dm0_ = (float)dmr[k][0], dm1_ = (float)dmr[k][1];
        const float lm0_ = 1.0f - dm0_, lm1_ = 1.0f - dm1_;
        P0 *= lm0_; P1 *= lm1_;
        float nr_ = fmaf(lm0_, c0 * fr0 - s0 * fi0, dm0_ * (float)ur[k][0]);
        fi0 = lm0_ * (c0 * fi0 + s0 * fr0); fr0 = nr_;
        nr_ = fmaf(lm1_, c1 * fr1 - s1 * fi1, dm1_ * (float)ur[k][1]);
        fi1 = lm1_ * (c1 * fi1 + s1 * fr1); fr1 = nr_;
    }
    float br0 = 0.f, bi0 = 0.f, br1 = 0.f, bi1 = 0.f;
#pragma unroll
    for (int k = CL - 1; k >= 0; --k) STEP(k, br0, bi0, br1, bi1);

    // chunk decay A = (prod lam) * (c + i s)^CL  (rotation by squaring)
    float rc0 = c0, rs0 = s0, rc1 = c1, rs1 = s1;
#pragma unroll
    for (int q = 0; q < 4; ++q) {     // ^16
        float t0 = rc0 * rc0 - rs0 * rs0; rs0 = 2.f * rc0 * rs0; rc0 = t0;
        float t1 = rc1 * rc1 - rs1 * rs1; rs1 = 2.f * rc1 * rs1; rc1 = t1;
    }

    {
        float* e = ex[chunk][dpl];
        e[0]  = P0 * rc0; e[1]  = P0 * rs0;
        e[2]  = fr0;      e[3]  = fi0;
        e[4]  = br0;      e[5]  = bi0;
        e[6]  = P1 * rc1; e[7]  = P1 * rs1;
        e[8]  = fr1;      e[9]  = fi1;
        e[10] = br1;      e[11] = bi1;
    }
    __syncthreads();

    // fold carries: fwd from chunks < c (left to right), bwd from chunks > c
    float cfr0 = 0.f, cfi0 = 0.f, cfr1 = 0.f, cfi1 = 0.f;
    for (int cc = 0; cc < chunk; ++cc) {
        const float* e = ex[cc][dpl];
        float nr = e[2] + e[0] * cfr0 - e[1] * cfi0;
        cfi0     = e[3] + e[0] * cfi0 + e[1] * cfr0;
        cfr0 = nr;
        nr       = e[8] + e[6] * cfr1 - e[7] * cfi1;
        cfi1     = e[9] + e[6] * cfi1 + e[7] * cfr1;
        cfr1 = nr;
    }
    float cbr0 = 0.f, cbi0 = 0.f, cbr1 = 0.f, cbi1 = 0.f;
    for (int cc = CH - 1; cc > chunk; --cc) {
        const float* e = ex[cc][dpl];
        float nr = e[4] + e[0] * cbr0 - e[1] * cbi0;
        cbi0     = e[5] + e[0] * cbi0 + e[1] * cbr0;
        cbr0 = nr;
        nr       = e[10] + e[6] * cbr1 - e[7] * cbi1;
        cbi1     = e[11] + e[6] * cbi1 + e[7] * cbr1;
        cbr1 = nr;
    }

    // Pass B: re-scan with correct initial state
    float yr0 = cfr0, yi0 = cfi0, yr1 = cfr1, yi1 = cfi1;
    f16x2 fres[CL];
#pragma unroll
    for (int k = 0; k < CL; ++k) {
        STEP(k, yr0, yi0, yr1, yi1);
        f16x2 p; p[0] = (_Float16)yr0; p[1] = (_Float16)yr1;
        fres[k] = p;
    }
    yr0 = cbr0; yi0 = cbi0; yr1 = cbr1; yi1 = cbi1;
#pragma unroll
    for (int k = CL - 1; k >= 0; --k) {
        STEP(k, yr0, yi0, yr1, yi1);
        f16x2 o;
        o[0] = (_Float16)((float)fres[k][0] + yr0);
        o[1] = (_Float16)((float)fres[k][1] + yr1);
        *(f16x2*)&hout[cbase + (size_t)k * stride] = o;
    }
}
#undef STEP

// v = g * (ha+hb) * rsqrt(mean((ha+hb)^2)+1e-6), fp16. One block per row.
__global__ __launch_bounds__(256) void gate_rmsnorm(
    const _Float16* __restrict__ ha, const _Float16* __restrict__ hb,
    const _Float16* __restrict__ g, _Float16* __restrict__ v)
{
    const int row = blockIdx.x;
    const int t = threadIdx.x;
    const size_t b0 = (size_t)row * DD + t * 2;
    const f16x2 a = *(const f16x2*)&ha[b0];
    const f16x2 b = *(const f16x2*)&hb[b0];
    const float h0 = (float)a[0] + (float)b[0];
    const float h1 = (float)a[1] + (float)b[1];
    float ss = h0 * h0 + h1 * h1;
#pragma unroll
    for (int off = 32; off > 0; off >>= 1) ss += __shfl_down(ss, off, 64);
    __shared__ float wsum[4];
    __shared__ float rms_s;
    if ((t & 63) == 0) wsum[t >> 6] = ss;
    __syncthreads();
    if (t == 0) {
        const float tot = wsum[0] + wsum[1] + wsum[2] + wsum[3];
        rms_s = rsqrtf(tot * (1.0f / (float)DD) + 1e-6f);
    }
    __syncthreads();
    const float rms = rms_s;
    const f16x2 gg = *(const f16x2*)&g[b0];
    f16x2 o;
    o[0] = (_Float16)((float)gg[0] * h0 * rms);
    o[1] = (_Float16)((float)gg[1] * h1 * rms);
    *(f16x2*)&v[b0] = o;
}

extern "C" void kernel_launch(void* const* d_in, const int* in_sizes, int n_in,
                              void* d_out, int out_size, void* d_ws, size_t ws_size,
                              hipStream_t stream)
{
    const float* x     = (const float*)d_in[0];
    const float* lb    = (const float*)d_in[1];
    const float* W_in  = (const float*)d_in[2];
    const float* b_in  = (const float*)d_in[3];
    const float* W_f   = (const float*)d_in[4];
    const float* b_f   = (const float*)d_in[5];
    const float* theta = (const float*)d_in[6];
    const float* W_g   = (const float*)d_in[7];
    const float* b_g   = (const float*)d_in[8];
    const float* W_out = (const float*)d_in[9];
    const float* b_out = (const float*)d_in[10];

    float* out = (float*)d_out;
    char* wsb  = (char*)d_ws;

    // ws (98 MB): [0,32M) dm fp16 (later v)  [32M,64M) u fp16
    //             [64M,96M) g fp16           [96M,98M) WT fp16 [2048][512]
    _Float16* dm_v = (_Float16*)wsb;
    _Float16* u_b  = (_Float16*)(wsb + ELEMS * 2);
    _Float16* g_b  = (_Float16*)(wsb + ELEMS * 4);
    _Float16* WT   = (_Float16*)(wsb + ELEMS * 6);
    const size_t WSEG = (size_t)DD * DD;

    // d_out doubles as scratch: [0,32M) ha fp16; [32M,64M) x16, then hb fp16.
    _Float16* ha  = (_Float16*)d_out;
    _Float16* x16 = (_Float16*)((char*)d_out + ELEMS * 2);
    _Float16* hb  = x16;                 // x16 dead after gemm8p<0>

    prep<<<8448, 256, 0, stream>>>(x, x16, W_f, W_in, W_g, W_out, WT);

    gemm8p<0><<<768, 512, 0, stream>>>(x16, WT, b_f, b_in, b_g, lb,
                                       dm_v, u_b, g_b);

    scan2<<<4096, 256, 0, stream>>>(dm_v, u_b, theta, ha, hb);

    // v overwrites dm (dead after scan2)
    gate_rmsnorm<<<M_ROWS, 256, 0, stream>>>(ha, hb, g_b, dm_v);

    // out = v @ W_out^T + b_out  (overwrites all of d_out)
    gemm8p<1><<<256, 512, 0, stream>>>(dm_v, WT + 3 * WSEG, b_out, nullptr,
                                       nullptr, nullptr, out, nullptr, nullptr);
}

// Round 7
// 281.477 us; speedup vs baseline: 1.0192x; 1.0192x over previous
//
#include <hip/hip_runtime.h>
#include <math.h>

#define DD 512
#define HG 64
#define M_ROWS 32768                    // 8*64*64
#define ELEMS ((size_t)M_ROWS * DD)
#define LOG2E 1.44269504088896340736f

typedef __attribute__((ext_vector_type(8))) _Float16 f16x8;
typedef __attribute__((ext_vector_type(2))) _Float16 f16x2;
typedef __attribute__((ext_vector_type(4))) float f32x4;

__device__ __forceinline__ float fexp2_(float x) { return __builtin_amdgcn_exp2f(x); }
__device__ __forceinline__ float frcp_(float x)  { return __builtin_amdgcn_rcpf(x); }
// sigmoid(v) = 1/(1+exp2(-v*log2e)); inf-safe: exp2->inf => rcp->0
__device__ __forceinline__ float fsig_(float v)  { return frcp_(1.0f + fexp2_(-v * LOG2E)); }

// Fused prep: blocks [0,8192) convert x fp32->fp16; blocks [8192,8448)
// transpose+convert the four 512x512 weights into WT (fp16, N-major).
__global__ __launch_bounds__(256) void prep(
    const float* __restrict__ x, _Float16* __restrict__ x16,
    const float* __restrict__ W0, const float* __restrict__ W1,
    const float* __restrict__ W2, const float* __restrict__ W3,
    _Float16* __restrict__ WT)
{
    __shared__ float tile[64][65];
    if (blockIdx.x < 8192) {
        const size_t i = ((size_t)blockIdx.x * 256 + threadIdx.x) * 8;
        const float4 a = *(const float4*)&x[i];
        const float4 b = *(const float4*)&x[i + 4];
        f16x8 h;
        h[0] = (_Float16)a.x; h[1] = (_Float16)a.y;
        h[2] = (_Float16)a.z; h[3] = (_Float16)a.w;
        h[4] = (_Float16)b.x; h[5] = (_Float16)b.y;
        h[6] = (_Float16)b.z; h[7] = (_Float16)b.w;
        *(f16x8*)&x16[i] = h;
        return;
    }
    const int wb = blockIdx.x - 8192;       // 0..255
    const int z = wb >> 6;
    const int rem = wb & 63;
    const int n0 = (rem & 7) * 64, k0 = (rem >> 3) * 64;
    const float* W = (z == 0) ? W0 : (z == 1) ? W1 : (z == 2) ? W2 : W3;
    _Float16* dst = WT + (size_t)z * DD * DD;
    const int t = threadIdx.x;
    const int tr = t >> 6, tc = t & 63;
#pragma unroll
    for (int p = 0; p < 16; ++p)
        tile[p * 4 + tr][tc] = W[(size_t)(k0 + p * 4 + tr) * DD + n0 + tc];
    __syncthreads();
#pragma unroll
    for (int p = 0; p < 16; ++p) {
        const int nn = p * 4 + tr;
        dst[(size_t)(n0 + nn) * DD + k0 + tc] = (_Float16)tile[tc][nn];
    }
}

// ---------------------------------------------------------------------------
// 256x256 fp16 GEMM, BK=32, 4 LDS buffers, register-double-buffered frags.
// (Round-5 version: best measured, 80.6us, 0 bank conflicts.)
// Per K-step g: stage tile g+3 (4 global_load_lds/wave) || ds-read tile g+1
// frags (12 b128/wave) || 32 MFMA on tile g's frags; then vmcnt(4)+barrier.
// LDS layout XOR-swizzled: LDS[r][c8] = G[r][c8 ^ ((r>>1)&3)] (16B chunks),
// applied on BOTH staging source and ds_read chunk (both-sides rule).
// Compiler-scheduled lgkmcnt (counted, per-fragment) — no manual drain.
// MODE 0: A=x16, WT=[W_f|W_in|W_g]^T (N=1536), epilogues dm/u/g (fp16).
// MODE 1: A=v, WT=W_out^T (N=512), out f32 + bias.
// ---------------------------------------------------------------------------
template <int MODE>
__global__ __launch_bounds__(512, 2) void gemm8p(
    const _Float16* __restrict__ A, const _Float16* __restrict__ WT,
    const float* __restrict__ b0, const float* __restrict__ b1,
    const float* __restrict__ b2, const float* __restrict__ lb_ptr,
    void* __restrict__ o0, void* __restrict__ o1, void* __restrict__ o2)
{
    __shared__ __align__(16) _Float16 As[4][256][32];
    __shared__ __align__(16) _Float16 Bs[4][256][32];

    const int NB = (MODE == 0) ? 6 : 2;
    const int lin = blockIdx.x;
    const int xcd = lin & 7;
    const int qq  = lin >> 3;
    const int n_idx = qq % NB;
    const int mq  = qq / NB;
    const int m0 = (xcd + 8 * mq) * 256;      // same XCD -> same A strip
    const int n0 = n_idx * 256;

    const int tid  = threadIdx.x;
    const int wv   = tid >> 6;                // 0..7
    const int lane = tid & 63;
    const int wm = wv >> 2, wn = wv & 3;      // 2 x 4 wave grid
    const int lrow = lane & 15;
    const int lk   = lane >> 4;               // k-chunk 0..3 (8 f16 each)

    // staging: wave wv owns rows wv*32..wv*32+31; lane l -> row +=(l>>2),
    // LDS chunk (l&3).  Source chunk pre-swizzled: (l&3) ^ ((l>>3)&3).
    const int srow = wv * 32 + (lane >> 2);
    const int schk = ((lane & 3) ^ ((lane >> 3) & 3)) * 8;
    const _Float16* Ag = A  + (size_t)(m0 + srow) * DD + schk;
    const _Float16* Bg = WT + (size_t)(n0 + srow) * DD + schk;

    // fragment read chunk: lk ^ ((lrow>>1)&3)
    const int ksw = (lk ^ ((lrow >> 1) & 3)) * 8;

    f32x4 acc[8][4];
#pragma unroll
    for (int i = 0; i < 8; ++i)
#pragma unroll
        for (int j = 0; j < 4; ++j) acc[i][j] = (f32x4)(0.f);

#define STG(BUF_, KT_) do {                                                    \
    _Pragma("unroll")                                                          \
    for (int j_ = 0; j_ < 2; ++j_) {                                           \
        __builtin_amdgcn_global_load_lds(                                      \
            (const __attribute__((address_space(1))) void*)                    \
              (Ag + (size_t)(j_ * 16) * DD + (KT_) * 32),                      \
            (__attribute__((address_space(3))) void*)                          \
              &As[BUF_][wv * 32 + j_ * 16][0], 16, 0, 0);                      \
        __builtin_amdgcn_global_load_lds(                                      \
            (const __attribute__((address_space(1))) void*)                    \
              (Bg + (size_t)(j_ * 16) * DD + (KT_) * 32),                      \
            (__attribute__((address_space(3))) void*)                          \
              &Bs[BUF_][wv * 32 + j_ * 16][0], 16, 0, 0);                      \
    } } while (0)

#define LDF(FA_, FB_, BUF_) do {                                               \
    _Pragma("unroll")                                                          \
    for (int q_ = 0; q_ < 8; ++q_)                                             \
        FA_[q_] = *(const f16x8*)&As[BUF_][wm * 128 + q_ * 16 + lrow][ksw];    \
    _Pragma("unroll")                                                          \
    for (int n_ = 0; n_ < 4; ++n_)                                             \
        FB_[n_] = *(const f16x8*)&Bs[BUF_][wn * 64 + n_ * 16 + lrow][ksw];     \
    } while (0)

#define MM(FA_, FB_) do {                                                      \
    __builtin_amdgcn_s_setprio(1);                                             \
    _Pragma("unroll")                                                          \
    for (int q_ = 0; q_ < 8; ++q_)                                             \
    _Pragma("unroll")                                                          \
    for (int n_ = 0; n_ < 4; ++n_)                                             \
        acc[q_][n_] = __builtin_amdgcn_mfma_f32_16x16x32_f16(                  \
            FA_[q_], FB_[n_], acc[q_][n_], 0, 0, 0);                           \
    __builtin_amdgcn_s_setprio(0);                                             \
    } while (0)

#define BAR __builtin_amdgcn_s_barrier()
#define VM(N_) asm volatile("s_waitcnt vmcnt(" #N_ ")" ::: "memory")

    f16x8 FA0[8], FB0[4], FA1[8], FB1[4];

    // prologue: stage tiles 0,1,2 (12 loads/wave); retire 0,1; load frags(0).
    STG(0, 0); STG(1, 1); STG(2, 2);
    VM(4); BAR;
    LDF(FA0, FB0, 0);

#pragma unroll
    for (int g = 0; g < 16; ++g) {
        if (g + 3 < 16) STG((g + 3) & 3, g + 3);
        if (g + 1 < 16) {
            if (g & 1) LDF(FA0, FB0, (g + 1) & 3);
            else       LDF(FA1, FB1, (g + 1) & 3);
        }
        if (g & 1) MM(FA1, FB1);
        else       MM(FA0, FB0);
        if (g < 13)      { VM(4); BAR; }
        else if (g < 15) { VM(0); BAR; }
    }

#undef STG
#undef LDF
#undef MM
#undef BAR
#undef VM

    // epilogue: row = m0 + wm*128 + q*16 + lk*4 + r;  col = wn*64 + n*16 + lrow
    if (MODE == 0) {
        const int seg = n_idx >> 1;
        const float lbv = lb_ptr[0];
        const float* bias = (seg == 0) ? b0 : (seg == 1) ? b1 : b2;
        _Float16* outp = (seg == 0) ? (_Float16*)o0
                       : (seg == 1) ? (_Float16*)o1 : (_Float16*)o2;
        const int cbase = (n_idx & 1) * 256 + wn * 64;
#pragma unroll
        for (int q = 0; q < 8; ++q) {
            const int row = m0 + wm * 128 + q * 16 + lk * 4;
#pragma unroll
            for (int n = 0; n < 4; ++n) {
                const int col = cbase + n * 16 + lrow;
                const float bcol = bias[col];
#pragma unroll
                for (int r = 0; r < 4; ++r) {
                    const float v = acc[q][n][r] + bcol;
                    float res;
                    if (seg == 0)      res = (1.0f - lbv) * frcp_(1.0f + fexp2_(v * LOG2E));
                    else if (seg == 1) res = v * fsig_(v);
                    else               res = fsig_(v);
                    outp[(size_t)(row + r) * DD + col] = (_Float16)res;
                }
            }
        }
    } else {
        float* outp = (float*)o0;
#pragma unroll
        for (int q = 0; q < 8; ++q) {
            const int row = m0 + wm * 128 + q * 16 + lk * 4;
#pragma unroll
            for (int n = 0; n < 4; ++n) {
                const int col = n0 + wn * 64 + n * 16 + lrow;
                const float bcol = b0[col];
#pragma unroll
                for (int r = 0; r < 4; ++r)
                    outp[(size_t)(row + r) * DD + col] = acc[q][n][r] + bcol;
            }
        }
    }
}

// Chunk-parallel bidirectional scan. 64-step line split into CH=4 chunks of
// CL=16; linear recurrence => exact carry fix-up via LDS exchange.
// Blocks [0,2048): axis-1 (j) -> ha.  [2048,4096): axis-0 (i) -> hb.
// Each block: one line x 64 d-pairs x 4 chunks (tid = chunk*64 + dpl).
// lam = 1-dm, inp = dm*u; y <- lam*(rot y) + inp; out = fwd + bwd.
#define CH 4
#define CL 16

#define STEP(K, YR0, YI0, YR1, YI1) {                                      \
    const float dm0_ = (float)dmr[K][0], dm1_ = (float)dmr[K][1];          \
    const float lm0_ = 1.0f - dm0_, lm1_ = 1.0f - dm1_;                    \
    float nr_ = fmaf(lm0_, c0 * (YR0) - s0 * (YI0), dm0_ * (float)ur[K][0]); \
    YI0 = lm0_ * (c0 * (YI0) + s0 * (YR0)); YR0 = nr_;                     \
    nr_ = fmaf(lm1_, c1 * (YR1) - s1 * (YI1), dm1_ * (float)ur[K][1]);     \
    YI1 = lm1_ * (c1 * (YI1) + s1 * (YR1)); YR1 = nr_; }

__global__ __launch_bounds__(256, 4) void scan2(
    const _Float16* __restrict__ dm, const _Float16* __restrict__ u,
    const float* __restrict__ theta,
    _Float16* __restrict__ ha, _Float16* __restrict__ hb)
{
    __shared__ float ex[CH][64][13];   // pad 12->13: stride coprime w/ 32 banks

    const int blk  = blockIdx.x & 2047;
    const bool is_i = blockIdx.x >= 2048;
    const int tid   = threadIdx.x;
    const int chunk = tid >> 6;        // 0..3 (wave-uniform)
    const int dpl   = tid & 63;
    const int dpg   = blk & 3;         // 4 groups of 64 d-pairs
    const int line  = blk >> 2;        // 0..511
    const int d0    = (dpg * 64 + dpl) * 2;

    size_t base, stride;
    _Float16* hout;
    if (!is_i) {
        base = (size_t)line * (HG * DD) + d0; stride = DD; hout = ha;
    } else {
        const int bb = line >> 6, j = line & 63;
        base = (size_t)bb * (HG * HG * DD) + (size_t)j * DD + d0;
        stride = (size_t)HG * DD; hout = hb;
    }
    const size_t cbase = base + (size_t)(chunk * CL) * stride;

    float s0, c0, s1, c1;
    sincosf(theta[d0], &s0, &c0);
    sincosf(theta[d0 + 1], &s1, &c1);

    // stage the chunk's dm/u into registers (single global read per element)
    f16x2 dmr[CL], ur[CL];
#pragma unroll
    for (int k = 0; k < CL; ++k) {
        dmr[k] = *(const f16x2*)&dm[cbase + (size_t)k * stride];
        ur[k]  = *(const f16x2*)&u [cbase + (size_t)k * stride];
    }

    // Pass A: zero-init local fwd & bwd scans + decay magnitude product
    float fr0 = 0.f, fi0 = 0.f, fr1 = 0.f, fi1 = 0.f;
    float P0 = 1.f, P1 = 1.f;
#pragma unroll
    for (int k = 0; k < CL; ++k) {
        const float dm0_ = (float)dmr[k][0], dm1_ = (float)dmr[k][1];
        const float lm0_ = 1.0f - dm0_, lm1_ = 1.0f - dm1_;
        P0 *= lm0_; P1 *= lm1_;
        float nr_ = fmaf(lm0_, c0 * fr0 - s0 * fi0, dm0_ * (float)ur[k][0]);
        fi0 = lm0_ * (c0 * fi0 + s0 * fr0); fr0 = nr_;
        nr_ = fmaf(lm1_, c1 * fr1 - s1 * fi1, dm1_ * (float)ur[k][1]);
        fi1 = lm1_ * (c1 * fi1 + s1 * fr1); fr1 = nr_;
    }
    float br0 = 0.f, bi0 = 0.f, br1 = 0.f, bi1 = 0.f;
#pragma unroll
    for (int k = CL - 1; k >= 0; --k) STEP(k, br0, bi0, br1, bi1);

    // chunk decay A = (prod lam) * (c + i s)^CL  (rotation by squaring)
    float rc0 = c0, rs0 = s0, rc1 = c1, rs1 = s1;
#pragma unroll
    for (int q = 0; q < 4; ++q) {     // ^16
        float t0 = rc0 * rc0 - rs0 * rs0; rs0 = 2.f * rc0 * rs0; rc0 = t0;
        float t1 = rc1 * rc1 - rs1 * rs1; rs1 = 2.f * rc1 * rs1; rc1 = t1;
    }

    {
        float* e = ex[chunk][dpl];
        e[0]  = P0 * rc0; e[1]  = P0 * rs0;
        e[2]  = fr0;      e[3]  = fi0;
        e[4]  = br0;      e[5]  = bi0;
        e[6]  = P1 * rc1; e[7]  = P1 * rs1;
        e[8]  = fr1;      e[9]  = fi1;
        e[10] = br1;      e[11] = bi1;
    }
    __syncthreads();

    // fold carries: fwd from chunks < c (left to right), bwd from chunks > c
    float cfr0 = 0.f, cfi0 = 0.f, cfr1 = 0.f, cfi1 = 0.f;
    for (int cc = 0; cc < chunk; ++cc) {
        const float* e = ex[cc][dpl];
        float nr = e[2] + e[0] * cfr0 - e[1] * cfi0;
        cfi0     = e[3] + e[0] * cfi0 + e[1] * cfr0;
        cfr0 = nr;
        nr       = e[8] + e[6] * cfr1 - e[7] * cfi1;
        cfi1     = e[9] + e[6] * cfi1 + e[7] * cfr1;
        cfr1 = nr;
    }
    float cbr0 = 0.f, cbi0 = 0.f, cbr1 = 0.f, cbi1 = 0.f;
    for (int cc = CH - 1; cc > chunk; --cc) {
        const float* e = ex[cc][dpl];
        float nr = e[4] + e[0] * cbr0 - e[1] * cbi0;
        cbi0     = e[5] + e[0] * cbi0 + e[1] * cbr0;
        cbr0 = nr;
        nr       = e[10] + e[6] * cbr1 - e[7] * cbi1;
        cbi1     = e[11] + e[6] * cbi1 + e[7] * cbr1;
        cbr1 = nr;
    }

    // Pass B: re-scan with correct initial state
    float yr0 = cfr0, yi0 = cfi0, yr1 = cfr1, yi1 = cfi1;
    f16x2 fres[CL];
#pragma unroll
    for (int k = 0; k < CL; ++k) {
        STEP(k, yr0, yi0, yr1, yi1);
        f16x2 p; p[0] = (_Float16)yr0; p[1] = (_Float16)yr1;
        fres[k] = p;
    }
    yr0 = cbr0; yi0 = cbi0; yr1 = cbr1; yi1 = cbi1;
#pragma unroll
    for (int k = CL - 1; k >= 0; --k) {
        STEP(k, yr0, yi0, yr1, yi1);
        f16x2 o;
        o[0] = (_Float16)((float)fres[k][0] + yr0);
        o[1] = (_Float16)((float)fres[k][1] + yr1);
        *(f16x2*)&hout[cbase + (size_t)k * stride] = o;
    }
}
#undef STEP

// v = g * (ha+hb) * rsqrt(mean((ha+hb)^2)+1e-6), fp16.
// 4 waves/block; each wave owns 2 rows; lane l = f16x8 chunk l of the row
// (64 lanes x 8 f16 = 512 = DD). Pure shfl reduce: no LDS, no barriers.
__global__ __launch_bounds__(256) void gate_rmsnorm(
    const _Float16* __restrict__ ha, const _Float16* __restrict__ hb,
    const _Float16* __restrict__ g, _Float16* __restrict__ v)
{
    const int wave = threadIdx.x >> 6, lane = threadIdx.x & 63;
    const int row0 = blockIdx.x * 8 + wave * 2;
#pragma unroll
    for (int rr = 0; rr < 2; ++rr) {
        const size_t b0 = (size_t)(row0 + rr) * DD + lane * 8;
        const f16x8 a = *(const f16x8*)&ha[b0];
        const f16x8 b = *(const f16x8*)&hb[b0];
        float h[8];
        float ss = 0.f;
#pragma unroll
        for (int i = 0; i < 8; ++i) {
            h[i] = (float)a[i] + (float)b[i];
            ss += h[i] * h[i];
        }
#pragma unroll
        for (int off = 32; off > 0; off >>= 1) ss += __shfl_xor(ss, off, 64);
        const float rms = rsqrtf(ss * (1.0f / (float)DD) + 1e-6f);
        const f16x8 gg = *(const f16x8*)&g[b0];
        f16x8 o;
#pragma unroll
        for (int i = 0; i < 8; ++i)
            o[i] = (_Float16)((float)gg[i] * h[i] * rms);
        *(f16x8*)&v[b0] = o;
    }
}

extern "C" void kernel_launch(void* const* d_in, const int* in_sizes, int n_in,
                              void* d_out, int out_size, void* d_ws, size_t ws_size,
                              hipStream_t stream)
{
    const float* x     = (const float*)d_in[0];
    const float* lb    = (const float*)d_in[1];
    const float* W_in  = (const float*)d_in[2];
    const float* b_in  = (const float*)d_in[3];
    const float* W_f   = (const float*)d_in[4];
    const float* b_f   = (const float*)d_in[5];
    const float* theta = (const float*)d_in[6];
    const float* W_g   = (const float*)d_in[7];
    const float* b_g   = (const float*)d_in[8];
    const float* W_out = (const float*)d_in[9];
    const float* b_out = (const float*)d_in[10];

    float* out = (float*)d_out;
    char* wsb  = (char*)d_ws;

    // ws (98 MB): [0,32M) dm fp16 (later v)  [32M,64M) u fp16
    //             [64M,96M) g fp16           [96M,98M) WT fp16 [2048][512]
    _Float16* dm_v = (_Float16*)wsb;
    _Float16* u_b  = (_Float16*)(wsb + ELEMS * 2);
    _Float16* g_b  = (_Float16*)(wsb + ELEMS * 4);
    _Float16* WT   = (_Float16*)(wsb + ELEMS * 6);
    const size_t WSEG = (size_t)DD * DD;

    // d_out doubles as scratch: [0,32M) ha fp16; [32M,64M) x16, then hb fp16.
    _Float16* ha  = (_Float16*)d_out;
    _Float16* x16 = (_Float16*)((char*)d_out + ELEMS * 2);
    _Float16* hb  = x16;                 // x16 dead after gemm8p<0>

    prep<<<8448, 256, 0, stream>>>(x, x16, W_f, W_in, W_g, W_out, WT);

    gemm8p<0><<<768, 512, 0, stream>>>(x16, WT, b_f, b_in, b_g, lb,
                                       dm_v, u_b, g_b);

    scan2<<<4096, 256, 0, stream>>>(dm_v, u_b, theta, ha, hb);

    // v overwrites dm (dead after scan2)
    gate_rmsnorm<<<4096, 256, 0, stream>>>(ha, hb, g_b, dm_v);

    // out = v @ W_out^T + b_out  (overwrites all of d_out)
    gemm8p<1><<<256, 512, 0, stream>>>(dm_v, WT + 3 * WSEG, b_out, nullptr,
                                       nullptr, nullptr, out, nullptr, nullptr);
}